// Round 6
// baseline (76.002 us; speedup 1.0000x reference)
//
#include <hip/hip_runtime.h>
#include <hip/hip_bf16.h>

#define NN 8192
#define DD 128
#define STRIP 8              // 128-col tiles per block
#define NBLK (64 * 8)        // 64 row groups x 8 strips

using floatx4 = __attribute__((ext_vector_type(4))) float;
using shortx8 = __attribute__((ext_vector_type(8))) short;
typedef unsigned short ushort_t;

__device__ __forceinline__ unsigned bf16pair(float lo, float hi) {
    unsigned ulo = __float_as_uint(lo);
    ulo = (ulo + 0x7FFFu + ((ulo >> 16) & 1u)) >> 16;          // RNE bf16, low half
    unsigned uhi = __float_as_uint(hi);
    uhi = (uhi + 0x7FFFu + ((uhi >> 16) & 1u)) & 0xFFFF0000u;  // RNE bf16, high half
    return uhi | ulo;
}

// ---- prep: f32 -> bf16 (linear layout) + squared norms ----
__global__ void prep_kernel(const float* __restrict__ x, const float* __restrict__ y,
                            ushort_t* __restrict__ xb, ushort_t* __restrict__ yb,
                            float* __restrict__ xx, float* __restrict__ yy) {
    const int tid = threadIdx.x;
    const int r = blockIdx.x * 16 + (tid >> 4);
    const int c = tid & 15;

    {
        const float4* xv = reinterpret_cast<const float4*>(x) + r * 32 + c * 2;
        const float4 a = xv[0], b = xv[1];
        uint4 u;
        u.x = bf16pair(a.x, a.y); u.y = bf16pair(a.z, a.w);
        u.z = bf16pair(b.x, b.y); u.w = bf16pair(b.z, b.w);
        reinterpret_cast<uint4*>(xb)[r * 16 + c] = u;
        float s = a.x*a.x + a.y*a.y + a.z*a.z + a.w*a.w
                + b.x*b.x + b.y*b.y + b.z*b.z + b.w*b.w;
        #pragma unroll
        for (int off = 8; off; off >>= 1) s += __shfl_xor(s, off);
        if (c == 0) xx[r] = s;
    }
    {
        const float4* yv = reinterpret_cast<const float4*>(y) + r * 32 + c * 2;
        const float4 a = yv[0], b = yv[1];
        uint4 u;
        u.x = bf16pair(a.x, a.y); u.y = bf16pair(a.z, a.w);
        u.z = bf16pair(b.x, b.y); u.w = bf16pair(b.z, b.w);
        reinterpret_cast<uint4*>(yb)[r * 16 + c] = u;
        float s = a.x*a.x + a.y*a.y + a.z*a.z + a.w*a.w
                + b.x*b.x + b.y*b.y + b.z*b.z + b.w*b.w;
        #pragma unroll
        for (int off = 8; off; off >>= 1) s += __shfl_xor(s, off);
        if (c == 0) yy[r] = s;
    }
}

// ---- strip kernel: 8 tiles of 128x128 per block; A in regs, B global->VGPR.
// No LDS staging, no barriers in the main loop: waves run fully independent.
__global__ __launch_bounds__(512, 2) void
tile_kernel(const ushort_t* __restrict__ xb, const ushort_t* __restrict__ yb,
            const float* __restrict__ xx, const float* __restrict__ yy,
            float* __restrict__ partials) {
    __shared__ float red[8][4];

    const int by  = blockIdx.x >> 3;          // row group (128 rows)
    const int bx0 = (blockIdx.x & 7) * STRIP; // first col tile
    const int tid = threadIdx.x;
    const int wv = tid >> 6, lane = tid & 63;
    const int l15 = lane & 15, kq = lane >> 4;
    const int wr = (wv >> 1) * 32;   // wave: 32 rows
    const int wc = (wv & 1) * 64;    //       x 64 cols

    // ---- A fragments: 32 rows x K=128 per wave, loaded once (32 VGPRs) ----
    const shortx8* xv8 = reinterpret_cast<const shortx8*>(xb);
    shortx8 a_reg[4][2];   // [kk][m]
    #pragma unroll
    for (int m = 0; m < 2; ++m) {
        const int ra = by * 128 + wr + m * 16 + l15;
        #pragma unroll
        for (int kk = 0; kk < 4; ++kk)
            a_reg[kk][m] = xv8[ra * 16 + kk * 4 + kq];
    }
    const int r0 = wr + kq * 4;     // C layout: row = kq*4+j, col = l15

    // row norms (+1): 8 regs, block-invariant
    float xv1[2][4];
    #pragma unroll
    for (int m = 0; m < 2; ++m) {
        const floatx4 v = *reinterpret_cast<const floatx4*>(xx + by * 128 + wr + m * 16 + kq * 4);
        #pragma unroll
        for (int j = 0; j < 4; ++j) xv1[m][j] = v[j] + 1.0f;
    }

    // per-lane B base: row (wc + l15), k-chunk kq
    const shortx8* yv8 = reinterpret_cast<const shortx8*>(yb);
    const shortx8* blane = yv8 + (size_t)(wc + l15) * 16 + kq;

    floatx4 sev = {0.f, 0.f, 0.f, 0.f};
    float sl2a = 0.f, sl2b = 0.f, p_l2 = 0.f, p_e = 0.f;

    for (int t = 0; t < STRIP; ++t) {
        const int bx = bx0 + t;
        const shortx8* bt = blane + (size_t)bx * (128 * 16);
        const float yv0 = yy[bx * 128 + wc + l15];
        const float yv1 = yy[bx * 128 + wc + 16 + l15];

        // ---- MFMA over K=128, B fragments straight from L1/L2 ----
        floatx4 acc[2][4];
        #pragma unroll
        for (int m = 0; m < 2; ++m)
            #pragma unroll
            for (int n = 0; n < 4; ++n)
                acc[m][n] = (floatx4){0.f, 0.f, 0.f, 0.f};

        #pragma unroll
        for (int kk = 0; kk < 4; ++kk) {
            shortx8 b[4];
            #pragma unroll
            for (int n = 0; n < 4; ++n)
                b[n] = bt[n * 256 + kk * 4];   // row n*16+l15, chunk kk*4+kq
            #pragma unroll
            for (int m = 0; m < 2; ++m)
                #pragma unroll
                for (int n = 0; n < 4; ++n)
                    acc[m][n] = __builtin_amdgcn_mfma_f32_16x16x32_bf16(a_reg[kk][m], b[n], acc[m][n], 0, 0, 0);
        }

        const float y0p = yv0 + 1.0f, y1p = yv1 + 1.0f;

        if (bx == by) {
            // diagonal tile: per-element logs (need individual diag logits)
            #pragma unroll
            for (int m = 0; m < 2; ++m)
                #pragma unroll
                for (int n = 0; n < 4; ++n)
                    #pragma unroll
                    for (int j = 0; j < 4; ++j) {
                        const float pre = xv1[m][j] + ((n & 1) ? y1p : y0p) + (n >> 1) * 0.0f
                                        - 1.0f + yy[bx * 128 + wc + n * 16 + l15] + 1.0f
                                        - ((n & 1) ? yv1 : yv0) - ((n & 1) ? 0.0f : 0.0f);
                        const float tt = fmaxf(fmaf(-2.0f, acc[m][n][j], pre), 1.0f);
                        const float l2 = __builtin_amdgcn_logf(tt);
                        const float e  = __builtin_amdgcn_rcpf(tt);
                        sl2a += l2; sev[j] += e;
                        if (r0 + m * 16 + j == wc + n * 16 + l15) { p_l2 += l2; p_e += e; }
                    }
        } else {
            #pragma unroll
            for (int m = 0; m < 2; ++m) {
                floatx4 t0, t1, e0, e1;
                #pragma unroll
                for (int j = 0; j < 4; ++j) {
                    t0[j] = fmaxf(fmaf(-2.0f, acc[m][0][j], xv1[m][j] + yv0), 1.0f);
                    t1[j] = fmaxf(fmaf(-2.0f, acc[m][1][j], xv1[m][j] + yv1), 1.0f);
                }
                #pragma unroll
                for (int j = 0; j < 4; ++j) { e0[j] = __builtin_amdgcn_rcpf(t0[j]); e1[j] = __builtin_amdgcn_rcpf(t1[j]); }
                sev += e0; sev += e1;
                const float pr0 = ((t0[0] * t0[1]) * (t0[2] * t0[3]))
                                * ((t1[0] * t1[1]) * (t1[2] * t1[3]));
                const float yv2 = yy[bx * 128 + wc + 32 + l15] + 1.0f;
                const float yv3 = yy[bx * 128 + wc + 48 + l15] + 1.0f;
                #pragma unroll
                for (int j = 0; j < 4; ++j) {
                    t0[j] = fmaxf(fmaf(-2.0f, acc[m][2][j], xv1[m][j] + yv2 - 1.0f), 1.0f);
                    t1[j] = fmaxf(fmaf(-2.0f, acc[m][3][j], xv1[m][j] + yv3 - 1.0f), 1.0f);
                }
                #pragma unroll
                for (int j = 0; j < 4; ++j) { e0[j] = __builtin_amdgcn_rcpf(t0[j]); e1[j] = __builtin_amdgcn_rcpf(t1[j]); }
                sev += e0; sev += e1;
                const float pr1 = ((t0[0] * t0[1]) * (t0[2] * t0[3]))
                                * ((t1[0] * t1[1]) * (t1[2] * t1[3]));
                sl2a += __builtin_amdgcn_logf(pr0);
                sl2b += __builtin_amdgcn_logf(pr1);
            }
        }
    }

    // ---- block reduction ----
    float s_l2 = sl2a + sl2b;
    float s_e  = sev[0] + sev[1] + sev[2] + sev[3];
    #pragma unroll
    for (int off = 32; off; off >>= 1) {
        s_l2 += __shfl_down(s_l2, off);
        s_e  += __shfl_down(s_e,  off);
        p_l2 += __shfl_down(p_l2, off);
        p_e  += __shfl_down(p_e,  off);
    }
    if (lane == 0) {
        red[wv][0] = s_l2; red[wv][1] = s_e; red[wv][2] = p_l2; red[wv][3] = p_e;
    }
    __syncthreads();
    if (tid < 4) {
        float v = 0.f;
        #pragma unroll
        for (int w = 0; w < 8; ++w) v += red[w][tid];
        partials[blockIdx.x * 4 + tid] = v;
    }
}

// ---- final reduction + the 4 scalar outputs ----
__global__ void finalize_kernel(const float* __restrict__ partials, int nblocks,
                                float* __restrict__ out) {
    float4 v = {0.f, 0.f, 0.f, 0.f};
    for (int i = threadIdx.x; i < nblocks; i += 256) {
        const float4 p = reinterpret_cast<const float4*>(partials)[i];
        v.x += p.x; v.y += p.y; v.z += p.z; v.w += p.w;
    }
    #pragma unroll
    for (int off = 32; off; off >>= 1) {
        v.x += __shfl_down(v.x, off);
        v.y += __shfl_down(v.y, off);
        v.z += __shfl_down(v.z, off);
        v.w += __shfl_down(v.w, off);
    }
    __shared__ float red[4][4];
    const int wv = threadIdx.x >> 6, lane = threadIdx.x & 63;
    if (lane == 0) { red[wv][0] = v.x; red[wv][1] = v.y; red[wv][2] = v.z; red[wv][3] = v.w; }
    __syncthreads();
    if (threadIdx.x == 0) {
        double Sl2 = 0, Se = 0, Pl2 = 0, Pe = 0;
        for (int w = 0; w < 4; ++w) {
            Sl2 += red[w][0]; Se += red[w][1]; Pl2 += red[w][2]; Pe += red[w][3];
        }
        const double LN2 = 0.6931471805599453;
        const double Sl = -LN2 * Sl2;   // sum of logits over all pairs (natural log)
        const double Pl = -LN2 * Pl2;   // sum over diagonal
        const double Nd = (double)NN;
        const double Md = Nd * (Nd - 1.0);
        const double mean_pos = Pl / Nd;
        const double mean_neg = (Sl - Pl) / Md;
        const double sumexp_neg = Se - Pe;
        const double lb = log(sumexp_neg) - log(Md);
        const double repulsion = sumexp_neg / (Md * exp(lb));
        const double loss = -(mean_pos - lb) + repulsion;   // EMBED_DECAY == 0
        out[0] = (float)mean_pos;
        out[1] = (float)mean_neg;
        out[2] = (float)lb;
        out[3] = (float)loss;
    }
}

extern "C" void kernel_launch(void* const* d_in, const int* in_sizes, int n_in,
                              void* d_out, int out_size, void* d_ws, size_t ws_size,
                              hipStream_t stream) {
    (void)in_sizes; (void)n_in; (void)out_size; (void)ws_size;
    const float* zx = (const float*)d_in[0];
    const float* zy = (const float*)d_in[1];
    float* out = (float*)d_out;
    char* ws = (char*)d_ws;

    float*    xx       = (float*)(ws);                        // 32 KB
    float*    yy       = (float*)(ws + (32 << 10));           // 32 KB
    float*    partials = (float*)(ws + (64 << 10));           // 8 KB used
    ushort_t* xb       = (ushort_t*)(ws + (128 << 10));       // 2 MB
    ushort_t* yb       = (ushort_t*)(ws + (128 << 10) + (2 << 20)); // 2 MB

    hipLaunchKernelGGL(prep_kernel, dim3(NN / 16), dim3(256), 0, stream, zx, zy, xb, yb, xx, yy);
    hipLaunchKernelGGL(tile_kernel, dim3(NBLK), dim3(512), 0, stream, xb, yb, xx, yy, partials);
    hipLaunchKernelGGL(finalize_kernel, dim3(1), dim3(256), 0, stream, partials, NBLK, out);
}

// Round 7
// 48.752 us; speedup vs baseline: 1.5590x; 1.5590x over previous
//
#include <hip/hip_runtime.h>
#include <hip/hip_bf16.h>

#define NN 8192
#define DD 128
#define STRIP 16             // 128-col tiles per block
#define NBLK (64 * 4)        // 64 row groups x 4 strips = 256 blocks = 1/CU

using floatx4 = __attribute__((ext_vector_type(4))) float;
using shortx8 = __attribute__((ext_vector_type(8))) short;
typedef unsigned short ushort_t;

__device__ __forceinline__ unsigned bf16pair(float lo, float hi) {
    unsigned ulo = __float_as_uint(lo);
    ulo = (ulo + 0x7FFFu + ((ulo >> 16) & 1u)) >> 16;          // RNE bf16, low half
    unsigned uhi = __float_as_uint(hi);
    uhi = (uhi + 0x7FFFu + ((uhi >> 16) & 1u)) & 0xFFFF0000u;  // RNE bf16, high half
    return uhi | ulo;
}

// ---- prep: f32 -> bf16 (linear layout) + squared norms ----
__global__ void prep_kernel(const float* __restrict__ x, const float* __restrict__ y,
                            ushort_t* __restrict__ xb, ushort_t* __restrict__ yb,
                            float* __restrict__ xx, float* __restrict__ yy) {
    const int tid = threadIdx.x;
    const int r = blockIdx.x * 16 + (tid >> 4);
    const int c = tid & 15;

    {
        const float4* xv = reinterpret_cast<const float4*>(x) + r * 32 + c * 2;
        const float4 a = xv[0], b = xv[1];
        uint4 u;
        u.x = bf16pair(a.x, a.y); u.y = bf16pair(a.z, a.w);
        u.z = bf16pair(b.x, b.y); u.w = bf16pair(b.z, b.w);
        reinterpret_cast<uint4*>(xb)[r * 16 + c] = u;
        float s = a.x*a.x + a.y*a.y + a.z*a.z + a.w*a.w
                + b.x*b.x + b.y*b.y + b.z*b.z + b.w*b.w;
        #pragma unroll
        for (int off = 8; off; off >>= 1) s += __shfl_xor(s, off);
        if (c == 0) xx[r] = s;
    }
    {
        const float4* yv = reinterpret_cast<const float4*>(y) + r * 32 + c * 2;
        const float4 a = yv[0], b = yv[1];
        uint4 u;
        u.x = bf16pair(a.x, a.y); u.y = bf16pair(a.z, a.w);
        u.z = bf16pair(b.x, b.y); u.w = bf16pair(b.z, b.w);
        reinterpret_cast<uint4*>(yb)[r * 16 + c] = u;
        float s = a.x*a.x + a.y*a.y + a.z*a.z + a.w*a.w
                + b.x*b.x + b.y*b.y + b.z*b.z + b.w*b.w;
        #pragma unroll
        for (int off = 8; off; off >>= 1) s += __shfl_xor(s, off);
        if (c == 0) yy[r] = s;
    }
}

// ---- strip kernel: 16 tiles of 128x128 per block; A in regs (64x128/wave),
// B global->VGPR with cross-tile rotated prefetch. No LDS, no main-loop barriers.
__global__ __launch_bounds__(512, 2) void
tile_kernel(const ushort_t* __restrict__ xb, const ushort_t* __restrict__ yb,
            const float* __restrict__ xx, const float* __restrict__ yy,
            float* __restrict__ partials) {
    __shared__ float red[8][4];

    const int by  = blockIdx.x >> 2;            // row group (128 rows)
    const int bx0 = (blockIdx.x & 3) * STRIP;   // first col tile
    const int tid = threadIdx.x;
    const int wv = tid >> 6, lane = tid & 63;
    const int l15 = lane & 15, kq = lane >> 4;
    const int wr = (wv >> 2) * 64;   // wave: 64 rows
    const int wc = (wv & 3) * 32;    //       x 32 cols

    // ---- A fragments: 64 rows x K=128 per wave, loaded once (64 VGPRs) ----
    const shortx8* xv8 = reinterpret_cast<const shortx8*>(xb);
    shortx8 a_reg[4][4];   // [kk][m]
    #pragma unroll
    for (int m = 0; m < 4; ++m) {
        const int ra = by * 128 + wr + m * 16 + l15;
        #pragma unroll
        for (int kk = 0; kk < 4; ++kk)
            a_reg[kk][m] = xv8[ra * 16 + kk * 4 + kq];
    }
    const int r0 = wr + kq * 4;     // C layout: row = kq*4+j, col = l15

    // row norms (+1): 16 regs, block-invariant
    float xv1[4][4];
    #pragma unroll
    for (int m = 0; m < 4; ++m) {
        const floatx4 v = *reinterpret_cast<const floatx4*>(xx + by * 128 + wr + m * 16 + kq * 4);
        #pragma unroll
        for (int j = 0; j < 4; ++j) xv1[m][j] = v[j] + 1.0f;
    }

    // per-lane B base: row (wc + n*16 + l15), k-chunk (kk*4 + kq)
    const shortx8* yv8 = reinterpret_cast<const shortx8*>(yb);
    const shortx8* blane = yv8 + (size_t)(wc + l15) * 16 + kq;

    // ---- prologue: load B fragments for tile 0 (32 VGPRs) ----
    shortx8 b[2][4];   // [n][kk]
    {
        const shortx8* bt = blane + (size_t)bx0 * 2048;
        #pragma unroll
        for (int n = 0; n < 2; ++n)
            #pragma unroll
            for (int kk = 0; kk < 4; ++kk)
                b[n][kk] = bt[n * 256 + kk * 4];
    }

    floatx4 sev = {0.f, 0.f, 0.f, 0.f};
    float sl2a = 0.f, sl2b = 0.f, p_l2 = 0.f, p_e = 0.f;

    for (int t = 0; t < STRIP; ++t) {
        const int bx = bx0 + t;
        // column norms for this tile (land during MFMA)
        const float yv0 = yy[bx * 128 + wc + l15];
        const float yv1 = yy[bx * 128 + wc + 16 + l15];

        // ---- MFMA over K=128 (waits on b loaded last iteration) ----
        floatx4 acc[4][2];
        #pragma unroll
        for (int m = 0; m < 4; ++m) {
            acc[m][0] = (floatx4){0.f, 0.f, 0.f, 0.f};
            acc[m][1] = (floatx4){0.f, 0.f, 0.f, 0.f};
        }
        #pragma unroll
        for (int kk = 0; kk < 4; ++kk)
            #pragma unroll
            for (int m = 0; m < 4; ++m) {
                acc[m][0] = __builtin_amdgcn_mfma_f32_16x16x32_bf16(a_reg[kk][m], b[0][kk], acc[m][0], 0, 0, 0);
                acc[m][1] = __builtin_amdgcn_mfma_f32_16x16x32_bf16(a_reg[kk][m], b[1][kk], acc[m][1], 0, 0, 0);
            }

        // ---- issue next tile's B loads; they complete under the epilogue ----
        if (t + 1 < STRIP) {
            const shortx8* bt = blane + (size_t)(bx + 1) * 2048;
            #pragma unroll
            for (int n = 0; n < 2; ++n)
                #pragma unroll
                for (int kk = 0; kk < 4; ++kk)
                    b[n][kk] = bt[n * 256 + kk * 4];
        }

        // ---- fused epilogue (long VALU/trans stretch hides the prefetch) ----
        if (bx == by) {
            // diagonal tile: per-element logs (need individual diag logits)
            #pragma unroll
            for (int m = 0; m < 4; ++m)
                #pragma unroll
                for (int n = 0; n < 2; ++n)
                    #pragma unroll
                    for (int j = 0; j < 4; ++j) {
                        const float tt = fmaxf(fmaf(-2.0f, acc[m][n][j], xv1[m][j] + (n ? yv1 : yv0)), 1.0f);
                        const float l2 = __builtin_amdgcn_logf(tt);
                        const float e  = __builtin_amdgcn_rcpf(tt);
                        sl2a += l2; sev[j] += e;
                        if (r0 + m * 16 + j == wc + n * 16 + l15) { p_l2 += l2; p_e += e; }
                    }
        } else {
            #pragma unroll
            for (int m = 0; m < 4; ++m) {
                floatx4 t0, t1, e0, e1;
                #pragma unroll
                for (int j = 0; j < 4; ++j) {
                    t0[j] = fmaxf(fmaf(-2.0f, acc[m][0][j], xv1[m][j] + yv0), 1.0f);
                    t1[j] = fmaxf(fmaf(-2.0f, acc[m][1][j], xv1[m][j] + yv1), 1.0f);
                }
                #pragma unroll
                for (int j = 0; j < 4; ++j) {
                    e0[j] = __builtin_amdgcn_rcpf(t0[j]);
                    e1[j] = __builtin_amdgcn_rcpf(t1[j]);
                }
                sev += e0; sev += e1;
                // one log per 8 elements: prod <= ~600^8, safely in f32 range
                const float pr = ((t0[0] * t0[1]) * (t0[2] * t0[3]))
                               * ((t1[0] * t1[1]) * (t1[2] * t1[3]));
                if (m & 1) sl2b += __builtin_amdgcn_logf(pr);
                else       sl2a += __builtin_amdgcn_logf(pr);
            }
        }
    }

    // ---- block reduction ----
    float s_l2 = sl2a + sl2b;
    float s_e  = sev[0] + sev[1] + sev[2] + sev[3];
    #pragma unroll
    for (int off = 32; off; off >>= 1) {
        s_l2 += __shfl_down(s_l2, off);
        s_e  += __shfl_down(s_e,  off);
        p_l2 += __shfl_down(p_l2, off);
        p_e  += __shfl_down(p_e,  off);
    }
    if (lane == 0) {
        red[wv][0] = s_l2; red[wv][1] = s_e; red[wv][2] = p_l2; red[wv][3] = p_e;
    }
    __syncthreads();
    if (tid < 4) {
        float v = 0.f;
        #pragma unroll
        for (int w = 0; w < 8; ++w) v += red[w][tid];
        partials[blockIdx.x * 4 + tid] = v;
    }
}

// ---- final reduction + the 4 scalar outputs ----
__global__ void finalize_kernel(const float* __restrict__ partials, int nblocks,
                                float* __restrict__ out) {
    float4 v = {0.f, 0.f, 0.f, 0.f};
    for (int i = threadIdx.x; i < nblocks; i += 256) {
        const float4 p = reinterpret_cast<const float4*>(partials)[i];
        v.x += p.x; v.y += p.y; v.z += p.z; v.w += p.w;
    }
    #pragma unroll
    for (int off = 32; off; off >>= 1) {
        v.x += __shfl_down(v.x, off);
        v.y += __shfl_down(v.y, off);
        v.z += __shfl_down(v.z, off);
        v.w += __shfl_down(v.w, off);
    }
    __shared__ float red[4][4];
    const int wv = threadIdx.x >> 6, lane = threadIdx.x & 63;
    if (lane == 0) { red[wv][0] = v.x; red[wv][1] = v.y; red[wv][2] = v.z; red[wv][3] = v.w; }
    __syncthreads();
    if (threadIdx.x == 0) {
        double Sl2 = 0, Se = 0, Pl2 = 0, Pe = 0;
        for (int w = 0; w < 4; ++w) {
            Sl2 += red[w][0]; Se += red[w][1]; Pl2 += red[w][2]; Pe += red[w][3];
        }
        const double LN2 = 0.6931471805599453;
        const double Sl = -LN2 * Sl2;   // sum of logits over all pairs (natural log)
        const double Pl = -LN2 * Pl2;   // sum over diagonal
        const double Nd = (double)NN;
        const double Md = Nd * (Nd - 1.0);
        const double mean_pos = Pl / Nd;
        const double mean_neg = (Sl - Pl) / Md;
        const double sumexp_neg = Se - Pe;
        const double lb = log(sumexp_neg) - log(Md);
        const double repulsion = sumexp_neg / (Md * exp(lb));
        const double loss = -(mean_pos - lb) + repulsion;   // EMBED_DECAY == 0
        out[0] = (float)mean_pos;
        out[1] = (float)mean_neg;
        out[2] = (float)lb;
        out[3] = (float)loss;
    }
}

extern "C" void kernel_launch(void* const* d_in, const int* in_sizes, int n_in,
                              void* d_out, int out_size, void* d_ws, size_t ws_size,
                              hipStream_t stream) {
    (void)in_sizes; (void)n_in; (void)out_size; (void)ws_size;
    const float* zx = (const float*)d_in[0];
    const float* zy = (const float*)d_in[1];
    float* out = (float*)d_out;
    char* ws = (char*)d_ws;

    float*    xx       = (float*)(ws);                        // 32 KB
    float*    yy       = (float*)(ws + (32 << 10));           // 32 KB
    float*    partials = (float*)(ws + (64 << 10));           // 4 KB used
    ushort_t* xb       = (ushort_t*)(ws + (128 << 10));       // 2 MB
    ushort_t* yb       = (ushort_t*)(ws + (128 << 10) + (2 << 20)); // 2 MB

    hipLaunchKernelGGL(prep_kernel, dim3(NN / 16), dim3(256), 0, stream, zx, zy, xb, yb, xx, yy);
    hipLaunchKernelGGL(tile_kernel, dim3(NBLK), dim3(512), 0, stream, xb, yb, xx, yy, partials);
    hipLaunchKernelGGL(finalize_kernel, dim3(1), dim3(256), 0, stream, partials, NBLK, out);
}